// Round 6
// baseline (442.305 us; speedup 1.0000x reference)
//
#include <hip/hip_runtime.h>

// Problem constants
#define M_DIM 8192   // 4*2048
#define N_DIM 4096   // OUT
#define K_DIM 4096   // IN
#define L_BLK 2097152  // OUT*IN/8
#define K2 8192      // bytes per bf16 row of K_DIM

typedef __attribute__((ext_vector_type(8))) short short8;
typedef __attribute__((ext_vector_type(8))) unsigned short ushort8;
typedef __attribute__((ext_vector_type(4))) float f32x4;

__device__ __forceinline__ unsigned short f2bf(float f) {
  unsigned int u = __float_as_uint(f);
  unsigned int r = (u + 0x7fffu + ((u >> 16) & 1u)) >> 16;
  return (unsigned short)r;
}

__device__ __forceinline__ void gld16(const void* g, void* l) {
  __builtin_amdgcn_global_load_lds(
      (const __attribute__((address_space(1))) void*)g,
      (__attribute__((address_space(3))) void*)l, 16, 0, 0);
}

// ---------------- Fused preprocessing: dequant (blocks 0..8191) + xconv (rest)
__global__ void prep_kernel(const float* __restrict__ cb,
                            const int* __restrict__ idx,
                            const int* __restrict__ base,
                            const float* __restrict__ scale,
                            const float* __restrict__ zero,
                            const float* __restrict__ x,
                            unsigned short* __restrict__ W,
                            unsigned short* __restrict__ xb) {
  if (blockIdx.x < L_BLK / 256) {
    const int b = blockIdx.x * 256 + threadIdx.x;   // one per 8-elem block
    const int o = b >> 9;                            // (b*8)/4096
    const float s = scale[o];
    const float z = zero[o];
    const int ci = idx[b];
    const float4* crow = (const float4*)(cb + (size_t)ci * 8);
    float4 c0 = crow[0], c1 = crow[1];
    const int4* brow = (const int4*)(base + (size_t)b * 8);
    int4 b0 = brow[0], b1 = brow[1];
    float a[8]  = {c0.x, c0.y, c0.z, c0.w, c1.x, c1.y, c1.z, c1.w};
    int   bi[8] = {b0.x, b0.y, b0.z, b0.w, b1.x, b1.y, b1.z, b1.w};
    union { unsigned short h[8]; ushort8 v; } u;
#pragma unroll
    for (int d = 0; d < 8; ++d) {
      float sg = 1.0f / (1.0f + __expf(-a[d]));
      float r = fminf(fmaxf(sg * 1.2f - 0.1f, 0.0f), 1.0f);
      float q = fminf(fmaxf((float)bi[d] + r + z, 0.0f), 15.0f);
      u.h[d] = f2bf(s * (q - z));
    }
    *(ushort8*)(W + (size_t)b * 8) = u.v;
  } else {
    const size_t i = (size_t)(blockIdx.x - L_BLK / 256) * 256 + threadIdx.x;
    const float4* X = (const float4*)x;
    float4 a0 = X[i * 2], a1 = X[i * 2 + 1];
    float f[8] = {a0.x, a0.y, a0.z, a0.w, a1.x, a1.y, a1.z, a1.w};
    union { unsigned short h[8]; ushort8 v; } u;
#pragma unroll
    for (int d = 0; d < 8; ++d) u.h[d] = f2bf(f[d]);
    *(ushort8*)(xb + i * 8) = u.v;
  }
}

// ---------------- GEMM: C[m,n] = sum_k A[m,k]*B[n,k] + bias[n]
// FAT-WAVE variant: 256x256 tile, BK=64, 4 waves (2Mx2N), per-wave output
// 128x128 (acc[8][8]). Per-CU LDS-read traffic drops 192->128 KB/tile
// (amplification x3 -> x2). 4-phase schedule, counted vmcnt (VMW(12) once
// per tile, 3-phase cover), plain s_barrier + compiler counted lgkmcnt.
// XOR-swizzled LDS (bank-conflict-free, verified round 2).

#define VMW(N) asm volatile("s_waitcnt vmcnt(" #N ")" ::: "memory")
#define BAR __builtin_amdgcn_s_barrier()

// read ALL B fragments for a tile (16 x ds_read_b128) -> bf[8][2]
#define RDB_ALL(BUFO) \
  _Pragma("unroll") for (int n = 0; n < 8; ++n) \
  _Pragma("unroll") for (int kk = 0; kk < 2; ++kk) \
    bf[n][kk] = *(const short8*)(lds + (BUFO) + 32768 + \
        (wn * 128 + n * 16 + r16) * 128 + (acol0 ^ (kk << 6)));

// read A fragments for m-pair P (4 x ds_read_b128)
#define RDA(BUFO, P) \
  _Pragma("unroll") for (int mi = 0; mi < 2; ++mi) \
  _Pragma("unroll") for (int kk = 0; kk < 2; ++kk) \
    af[mi][kk] = *(const short8*)(lds + (BUFO) + \
        (wm * 128 + (2 * (P) + mi) * 16 + r16) * 128 + (acol0 ^ (kk << 6)));

// MFMA m-pair P x all 8 n (32 MFMA) in a setprio bracket (T5)
#define FMQ(P) do { \
  __builtin_amdgcn_s_setprio(1); \
  _Pragma("unroll") for (int kk = 0; kk < 2; ++kk) \
  _Pragma("unroll") for (int mi = 0; mi < 2; ++mi) \
  _Pragma("unroll") for (int n = 0; n < 8; ++n) \
    acc[2 * (P) + mi][n] = __builtin_amdgcn_mfma_f32_16x16x32_bf16( \
        af[mi][kk], bf[n][kk], acc[2 * (P) + mi][n], 0, 0, 0); \
  __builtin_amdgcn_s_setprio(0); \
} while (0)

// One K-tile (4 phases). Stage map (race-free by barrier construction):
// P1 -> A1,A3 of t+1 (into NXT; those rows' last read was t-1's P4);
// P2 -> B0,B1 of t+2 (into CUR; all B read in P1);
// P3 -> B2,B3 of t+2; P4 -> A0,A2 of t+2 (rows last read in P2).
// VMW(12) at P4: retires prev-P2..P4 + this-P1 (exactly what t+1.P1 reads),
// keeps this tile's P2-P4 12 loads in flight.
#define ITER(CUR, NXT, T) do { \
  /* P1 */ RDA(CUR, 0); RDB_ALL(CUR); \
  stA(NXT, 1, (T) + 1); stA(NXT, 3, (T) + 1); \
  BAR; FMQ(0); BAR; \
  /* P2 */ RDA(CUR, 1); \
  stB(CUR, 0, (T) + 2); stB(CUR, 1, (T) + 2); \
  BAR; FMQ(1); BAR; \
  /* P3 */ RDA(CUR, 2); \
  stB(CUR, 2, (T) + 2); stB(CUR, 3, (T) + 2); \
  BAR; FMQ(2); BAR; \
  /* P4 */ RDA(CUR, 3); \
  stA(CUR, 0, (T) + 2); stA(CUR, 2, (T) + 2); \
  VMW(12); BAR; FMQ(3); BAR; \
} while (0)

__global__ __launch_bounds__(256, 1)
void gemm_bt(const unsigned short* __restrict__ A,
             const unsigned short* __restrict__ B,
             const float* __restrict__ bias,
             float* __restrict__ C) {
  __shared__ char lds[131072];  // 2 bufs x (A 32K | B 32K)
  const int tid = threadIdx.x;
  const int lane = tid & 63;
  const int w = tid >> 6;       // 0..3
  const int wm = w >> 1;        // 0..1  (wave row: 128 rows)
  const int wn = w & 1;         // 0..1  (wave col: 128 cols)
  const int r16 = lane & 15;
  const int g = lane >> 4;
  const int acol0 = (g << 4) ^ ((r16 & 7) << 4);

  // XCD-bijective block swizzle (512 % 8 == 0), bn-major chunks for B-panel L2 reuse
  const int s = (int)blockIdx.x;
  const int wg = (s & 7) * 64 + (s >> 3);
  const int bm = wg & 31;
  const int bn = wg >> 5;

  const char* Abase = (const char*)A + (size_t)bm * 256 * K2;
  const char* Bbase = (const char*)B + (size_t)bn * 256 * K2;

  // staging: chunk = 64 rows x 128 B = 8 KiB; 2 gld16 per thread per chunk
  // (rows strow and strow+32). Inverse-swizzled global source, linear LDS
  // dest (rule #21): per-wave dest base is uniform, lanes fill base+lane*16.
  const int strow = (w << 3) + (lane >> 3);               // 0..31
  const int scol = ((lane & 7) << 4) ^ ((lane >> 3) << 4);  // (strow&7)==lane>>3

  auto stA = [&](int bo, int c, int kt) {
    const char* src = Abase + (size_t)(c * 64 + strow) * K2 + kt * 128 + scol;
    char* dst = lds + bo + c * 8192 + w * 1024;
    gld16(src, dst);
    gld16(src + (size_t)32 * K2, dst + 4096);
  };
  auto stB = [&](int bo, int c, int kt) {
    const char* src = Bbase + (size_t)(c * 64 + strow) * K2 + kt * 128 + scol;
    char* dst = lds + bo + 32768 + c * 8192 + w * 1024;
    gld16(src, dst);
    gld16(src + (size_t)32 * K2, dst + 4096);
  };

  f32x4 acc[8][8] = {};
  short8 bf[8][2];
  short8 af[2][2];

  // prologue: tile0 full (16 loads) + tile1's B0-3,A0,A2 (12 loads);
  // VMW(12) retires tile0's 16, keeps tile1's 12 in flight (steady invariant).
  stB(0, 0, 0); stB(0, 1, 0); stB(0, 2, 0); stB(0, 3, 0);
  stA(0, 0, 0); stA(0, 1, 0); stA(0, 2, 0); stA(0, 3, 0);
  stB(65536, 0, 1); stB(65536, 1, 1); stB(65536, 2, 1); stB(65536, 3, 1);
  stA(65536, 0, 1); stA(65536, 2, 1);
  VMW(12); BAR;

  // tiles 0..61 as 31 even/odd pairs
  for (int tp = 0; tp < 31; ++tp) {
    ITER(0, 65536, 2 * tp);
    ITER(65536, 0, 2 * tp + 1);
  }
  // tile 62 (CUR=0): stages only A1,A3 of t63; VMW(0) at P4 drains everything
  RDA(0, 0); RDB_ALL(0);
  stA(65536, 1, 63); stA(65536, 3, 63);
  BAR; FMQ(0); BAR;
  RDA(0, 1);
  BAR; FMQ(1); BAR;
  RDA(0, 2);
  BAR; FMQ(2); BAR;
  RDA(0, 3);
  VMW(0); BAR; FMQ(3); BAR;
  // tile 63 (buf 1): pure reads, no staging, no barriers needed
  RDA(65536, 0); RDB_ALL(65536);
  FMQ(0);
  RDA(65536, 1);
  FMQ(1);
  RDA(65536, 2);
  FMQ(2);
  RDA(65536, 3);
  FMQ(3);

  // epilogue: C/D layout col = lane&15, row = (lane>>4)*4 + j  [m89-verified]
  const int cb0 = bn * 256 + wn * 128 + r16;
  float bv[8];
#pragma unroll
  for (int n = 0; n < 8; ++n) bv[n] = bias[cb0 + n * 16];
#pragma unroll
  for (int m = 0; m < 8; ++m) {
#pragma unroll
    for (int j = 0; j < 4; ++j) {
      int row = bm * 256 + wm * 128 + m * 16 + g * 4 + j;
      float* Crow = C + (size_t)row * N_DIM + cb0;
#pragma unroll
      for (int n = 0; n < 8; ++n) Crow[n * 16] = acc[m][n][j] + bv[n];
    }
  }
}

extern "C" void kernel_launch(void* const* d_in, const int* in_sizes, int n_in,
                              void* d_out, int out_size, void* d_ws, size_t ws_size,
                              hipStream_t stream) {
  const float* x     = (const float*)d_in[0];
  const float* cb    = (const float*)d_in[1];
  const int*   idx   = (const int*)d_in[2];
  const int*   base  = (const int*)d_in[3];
  const float* scale = (const float*)d_in[4];
  const float* zero  = (const float*)d_in[5];
  const float* bias  = (const float*)d_in[6];
  float* out = (float*)d_out;

  // workspace: Wq bf16 [N,K] (32 MiB) | x bf16 [M,K] (64 MiB)
  unsigned short* Wq = (unsigned short*)d_ws;
  unsigned short* Xb = (unsigned short*)((char*)d_ws + (size_t)N_DIM * K_DIM * 2);

  const int prep_blocks = L_BLK / 256 + (M_DIM * K_DIM / 8) / 256;
  prep_kernel<<<prep_blocks, 256, 0, stream>>>(cb, idx, base, scale, zero, x, Wq, Xb);
  gemm_bt<<<(M_DIM / 256) * (N_DIM / 256), 256, 0, stream>>>(Xb, Wq, bias, out);
}

// Round 7
// 343.687 us; speedup vs baseline: 1.2869x; 1.2869x over previous
//
#include <hip/hip_runtime.h>

// Problem constants
#define M_DIM 8192   // 4*2048
#define N_DIM 4096   // OUT
#define K_DIM 4096   // IN
#define L_BLK 2097152  // OUT*IN/8
#define K2 8192      // bytes per bf16 row of K_DIM

typedef __attribute__((ext_vector_type(8))) short short8;
typedef __attribute__((ext_vector_type(8))) unsigned short ushort8;
typedef __attribute__((ext_vector_type(16))) float f32x16;

__device__ __forceinline__ unsigned short f2bf(float f) {
  unsigned int u = __float_as_uint(f);
  unsigned int r = (u + 0x7fffu + ((u >> 16) & 1u)) >> 16;
  return (unsigned short)r;
}

__device__ __forceinline__ void gld16(const void* g, void* l) {
  __builtin_amdgcn_global_load_lds(
      (const __attribute__((address_space(1))) void*)g,
      (__attribute__((address_space(3))) void*)l, 16, 0, 0);
}

// ---------------- Fused preprocessing: dequant (blocks 0..8191) + xconv (rest)
__global__ void prep_kernel(const float* __restrict__ cb,
                            const int* __restrict__ idx,
                            const int* __restrict__ base,
                            const float* __restrict__ scale,
                            const float* __restrict__ zero,
                            const float* __restrict__ x,
                            unsigned short* __restrict__ W,
                            unsigned short* __restrict__ xb) {
  if (blockIdx.x < L_BLK / 256) {
    const int b = blockIdx.x * 256 + threadIdx.x;   // one per 8-elem block
    const int o = b >> 9;                            // (b*8)/4096
    const float s = scale[o];
    const float z = zero[o];
    const int ci = idx[b];
    const float4* crow = (const float4*)(cb + (size_t)ci * 8);
    float4 c0 = crow[0], c1 = crow[1];
    const int4* brow = (const int4*)(base + (size_t)b * 8);
    int4 b0 = brow[0], b1 = brow[1];
    float a[8]  = {c0.x, c0.y, c0.z, c0.w, c1.x, c1.y, c1.z, c1.w};
    int   bi[8] = {b0.x, b0.y, b0.z, b0.w, b1.x, b1.y, b1.z, b1.w};
    union { unsigned short h[8]; ushort8 v; } u;
#pragma unroll
    for (int d = 0; d < 8; ++d) {
      float sg = 1.0f / (1.0f + __expf(-a[d]));
      float r = fminf(fmaxf(sg * 1.2f - 0.1f, 0.0f), 1.0f);
      float q = fminf(fmaxf((float)bi[d] + r + z, 0.0f), 15.0f);
      u.h[d] = f2bf(s * (q - z));
    }
    *(ushort8*)(W + (size_t)b * 8) = u.v;
  } else {
    const size_t i = (size_t)(blockIdx.x - L_BLK / 256) * 256 + threadIdx.x;
    const float4* X = (const float4*)x;
    float4 a0 = X[i * 2], a1 = X[i * 2 + 1];
    float f[8] = {a0.x, a0.y, a0.z, a0.w, a1.x, a1.y, a1.z, a1.w};
    union { unsigned short h[8]; ushort8 v; } u;
#pragma unroll
    for (int d = 0; d < 8; ++d) u.h[d] = f2bf(f[d]);
    *(ushort8*)(xb + i * 8) = u.v;
  }
}

// ---------------- GEMM: C[m,n] = sum_k A[m,k]*B[n,k] + bias[n]
// 256x256 tile, BK=64, 8 waves (2Mx4N), per-wave out 128x64.
// Round 7: 32x32x16 MFMA (pipe rate 2382-2495 vs 2075 TF) + TWO phases per
// K-tile (4 barriers/tile vs 8 — halves exposed barrier latency).
// Per wave per tile: 24 ds_read_b128 (16 A + 8 B), 32 MFMA.
// One VMW(6) per tile at P2 (1-2 phase cover, ~1900 cyc > 900 HBM latency).
// Race-freedom: every chunk overwrite issues >=1 barrier after the phase
// that last read it (P1 reads a0,a2+B; P2 reads a1,a3).
// XOR-swizzled LDS: addr = row*128 + (col ^ ((row&7)<<4)); 32-row fragment
// reads spread slot = (2ks+h)^(row&7) over all 8 slots -> 2/bank = free.

#define VMW(N) asm volatile("s_waitcnt vmcnt(" #N ")" ::: "memory")
#define BAR __builtin_amdgcn_s_barrier()

// read B fragments: nf in {0,1}, ks in 0..3 -> bf[nf][ks]
#define RDB(BUFO) \
  _Pragma("unroll") for (int nf = 0; nf < 2; ++nf) \
  _Pragma("unroll") for (int ks = 0; ks < 4; ++ks) \
    bf[nf][ks] = *(const short8*)(lds + (BUFO) + 32768 + \
        (wn * 64 + nf * 32 + l31) * 128 + ((ks * 32 + h16) ^ swz));

// read A fragments for m-frag pair {MF, MF+1} -> af[0..1][ks]
#define RDA2(BUFO, MF) \
  _Pragma("unroll") for (int mi = 0; mi < 2; ++mi) \
  _Pragma("unroll") for (int ks = 0; ks < 4; ++ks) \
    af[mi][ks] = *(const short8*)(lds + (BUFO) + \
        (wm * 128 + ((MF) + mi) * 32 + l31) * 128 + ((ks * 32 + h16) ^ swz));

// 16 MFMA for m-frags {MF, MF+1} x nf{0,1} x ks0..3, setprio bracket (T5)
#define FM2(MF) do { \
  __builtin_amdgcn_s_setprio(1); \
  _Pragma("unroll") for (int ks = 0; ks < 4; ++ks) \
  _Pragma("unroll") for (int mi = 0; mi < 2; ++mi) \
  _Pragma("unroll") for (int nf = 0; nf < 2; ++nf) \
    acc[(MF) + mi][nf] = __builtin_amdgcn_mfma_f32_32x32x16_bf16( \
        af[mi][ks], bf[nf][ks], acc[(MF) + mi][nf], 0, 0, 0); \
  __builtin_amdgcn_s_setprio(0); \
} while (0)

// One K-tile, 2 phases.
#define ITER(CUR, NXT, T) do { \
  /* P1: reads B all + A m0,m1 (chunks a0,a2); stage a1,a3 of t+1 */ \
  RDB(CUR); RDA2(CUR, 0); \
  stA(NXT, 1, (T) + 1); stA(NXT, 3, (T) + 1); \
  BAR; FM2(0); BAR; \
  /* P2: reads A m2,m3 (a1,a3); stage B0-3 + a0,a2 of t+2 */ \
  RDA2(CUR, 2); \
  stB(CUR, 0, (T) + 2); stB(CUR, 1, (T) + 2); \
  stB(CUR, 2, (T) + 2); stB(CUR, 3, (T) + 2); \
  stA(CUR, 0, (T) + 2); stA(CUR, 2, (T) + 2); \
  VMW(6); BAR; FM2(2); BAR; \
} while (0)

__global__ __launch_bounds__(512, 2)
void gemm_bt(const unsigned short* __restrict__ A,
             const unsigned short* __restrict__ B,
             const float* __restrict__ bias,
             float* __restrict__ C) {
  __shared__ char lds[131072];  // 2 bufs x (A 32K | B 32K)
  const int tid = threadIdx.x;
  const int lane = tid & 63;
  const int w = tid >> 6;       // 0..7
  const int wm = w >> 2;        // 0..1  (wave row: 128 rows)
  const int wn = w & 3;         // 0..3  (wave col: 64 cols)
  const int l31 = lane & 31;
  const int h16 = (lane >> 5) * 16;
  const int swz = (l31 & 7) << 4;

  // XCD-bijective block swizzle (512 % 8 == 0), bn-major chunks for B-panel L2 reuse
  const int s = (int)blockIdx.x;
  const int wg = (s & 7) * 64 + (s >> 3);
  const int bm = wg & 31;
  const int bn = wg >> 5;

  const char* Abase = (const char*)A + (size_t)bm * 256 * K2;
  const char* Bbase = (const char*)B + (size_t)bn * 256 * K2;

  // staging: chunk = 64 rows x 128 B = 8 KiB; one gld16 per thread per chunk.
  // Inverse-swizzled global source, linear LDS dest (rule #21).
  const int strow = tid >> 3;
  const int scol = ((tid & 7) * 16) ^ ((strow & 7) << 4);
  const int sdst = w * 1024;

  auto stA = [&](int bo, int c, int kt) {
    gld16(Abase + (size_t)(c * 64 + strow) * K2 + kt * 128 + scol,
          lds + bo + c * 8192 + sdst);
  };
  auto stB = [&](int bo, int c, int kt) {
    gld16(Bbase + (size_t)(c * 64 + strow) * K2 + kt * 128 + scol,
          lds + bo + 32768 + c * 8192 + sdst);
  };

  f32x16 acc[4][2] = {};
  short8 bf[2][4];
  short8 af[2][4];

  // prologue: tile0 all 8 chunks + tile1's B0-3,a0,a2 (6); VMW(6) retires
  // tile0's 8, keeps tile1's 6 in flight (steady-state invariant).
  stB(0, 0, 0); stB(0, 1, 0); stB(0, 2, 0); stB(0, 3, 0);
  stA(0, 0, 0); stA(0, 1, 0); stA(0, 2, 0); stA(0, 3, 0);
  stB(65536, 0, 1); stB(65536, 1, 1); stB(65536, 2, 1); stB(65536, 3, 1);
  stA(65536, 0, 1); stA(65536, 2, 1);
  VMW(6); BAR;

  // tiles 0..61 as 31 even/odd pairs
  for (int tp = 0; tp < 31; ++tp) {
    ITER(0, 65536, 2 * tp);
    ITER(65536, 0, 2 * tp + 1);
  }
  // tile 62 (CUR=0): stages only a1,a3 of t63 at P1; VMW(0) at P2 drains all
  RDB(0); RDA2(0, 0);
  stA(65536, 1, 63); stA(65536, 3, 63);
  BAR; FM2(0); BAR;
  RDA2(0, 2);
  VMW(0); BAR; FM2(2); BAR;
  // tile 63 (buf 1): pure reads, no staging, no barriers needed
  RDB(65536); RDA2(65536, 0);
  FM2(0);
  RDA2(65536, 2);
  FM2(2);

  // epilogue: 32x32 C/D layout: col = lane&31, row = (r&3)+8*(r>>2)+4*(lane>>5)
  // [m74/m101-verified]
  const int cb0 = bn * 256 + wn * 64 + l31;
  const int hr = (lane >> 5) * 2;  // 4*h packed into row formula below (x2 rows of 2)
  float bv0 = bias[cb0];
  float bv1 = bias[cb0 + 32];
#pragma unroll
  for (int mf = 0; mf < 4; ++mf) {
#pragma unroll
    for (int r = 0; r < 16; ++r) {
      int row = bm * 256 + wm * 128 + mf * 32 + (r & 3) + 8 * (r >> 2) + 2 * hr;
      float* Crow = C + (size_t)row * N_DIM + cb0;
      Crow[0]  = acc[mf][0][r] + bv0;
      Crow[32] = acc[mf][1][r] + bv1;
    }
  }
}

extern "C" void kernel_launch(void* const* d_in, const int* in_sizes, int n_in,
                              void* d_out, int out_size, void* d_ws, size_t ws_size,
                              hipStream_t stream) {
  const float* x     = (const float*)d_in[0];
  const float* cb    = (const float*)d_in[1];
  const int*   idx   = (const int*)d_in[2];
  const int*   base  = (const int*)d_in[3];
  const float* scale = (const float*)d_in[4];
  const float* zero  = (const float*)d_in[5];
  const float* bias  = (const float*)d_in[6];
  float* out = (float*)d_out;

  // workspace: Wq bf16 [N,K] (32 MiB) | x bf16 [M,K] (64 MiB)
  unsigned short* Wq = (unsigned short*)d_ws;
  unsigned short* Xb = (unsigned short*)((char*)d_ws + (size_t)N_DIM * K_DIM * 2);

  const int prep_blocks = L_BLK / 256 + (M_DIM * K_DIM / 8) / 256;
  prep_kernel<<<prep_blocks, 256, 0, stream>>>(cb, idx, base, scale, zero, x, Wq, Xb);
  gemm_bt<<<(M_DIM / 256) * (N_DIM / 256), 512, 0, stream>>>(Xb, Wq, bias, out);
}

// Round 8
// 321.140 us; speedup vs baseline: 1.3773x; 1.0702x over previous
//
#include <hip/hip_runtime.h>

// Problem constants
#define M_DIM 8192   // 4*2048
#define N_DIM 4096   // OUT
#define K_DIM 4096   // IN
#define L_BLK 2097152  // OUT*IN/8
#define K2 8192      // bytes per bf16 row of K_DIM

typedef __attribute__((ext_vector_type(8))) short short8;
typedef __attribute__((ext_vector_type(8))) unsigned short ushort8;
typedef __attribute__((ext_vector_type(4))) float f32x4;

__device__ __forceinline__ unsigned short f2bf(float f) {
  unsigned int u = __float_as_uint(f);
  unsigned int r = (u + 0x7fffu + ((u >> 16) & 1u)) >> 16;
  return (unsigned short)r;
}

__device__ __forceinline__ void gld16(const void* g, void* l) {
  __builtin_amdgcn_global_load_lds(
      (const __attribute__((address_space(1))) void*)g,
      (__attribute__((address_space(3))) void*)l, 16, 0, 0);
}

// ---------------- Fused preprocessing: dequant (blocks 0..8191) + xconv (rest)
__global__ void prep_kernel(const float* __restrict__ cb,
                            const int* __restrict__ idx,
                            const int* __restrict__ base,
                            const float* __restrict__ scale,
                            const float* __restrict__ zero,
                            const float* __restrict__ x,
                            unsigned short* __restrict__ W,
                            unsigned short* __restrict__ xb) {
  if (blockIdx.x < L_BLK / 256) {
    const int b = blockIdx.x * 256 + threadIdx.x;   // one per 8-elem block
    const int o = b >> 9;                            // (b*8)/4096
    const float s = scale[o];
    const float z = zero[o];
    const int ci = idx[b];
    const float4* crow = (const float4*)(cb + (size_t)ci * 8);
    float4 c0 = crow[0], c1 = crow[1];
    const int4* brow = (const int4*)(base + (size_t)b * 8);
    int4 b0 = brow[0], b1 = brow[1];
    float a[8]  = {c0.x, c0.y, c0.z, c0.w, c1.x, c1.y, c1.z, c1.w};
    int   bi[8] = {b0.x, b0.y, b0.z, b0.w, b1.x, b1.y, b1.z, b1.w};
    union { unsigned short h[8]; ushort8 v; } u;
#pragma unroll
    for (int d = 0; d < 8; ++d) {
      float sg = 1.0f / (1.0f + __expf(-a[d]));
      float r = fminf(fmaxf(sg * 1.2f - 0.1f, 0.0f), 1.0f);
      float q = fminf(fmaxf((float)bi[d] + r + z, 0.0f), 15.0f);
      u.h[d] = f2bf(s * (q - z));
    }
    *(ushort8*)(W + (size_t)b * 8) = u.v;
  } else {
    const size_t i = (size_t)(blockIdx.x - L_BLK / 256) * 256 + threadIdx.x;
    const float4* X = (const float4*)x;
    float4 a0 = X[i * 2], a1 = X[i * 2 + 1];
    float f[8] = {a0.x, a0.y, a0.z, a0.w, a1.x, a1.y, a1.z, a1.w};
    union { unsigned short h[8]; ushort8 v; } u;
#pragma unroll
    for (int d = 0; d < 8; ++d) u.h[d] = f2bf(f[d]);
    *(ushort8*)(xb + i * 8) = u.v;
  }
}

// ---------------- GEMM: C[m,n] = sum_k A[m,k]*B[n,k] + bias[n]
// 256x256 tile, BK=64, 8 waves (2Mx4N). Round 8: m201-faithful QUADRANT
// phases (m-half x n-half) with per-m-half B RE-READ: ds_read cadence
// 12/4/12/4 per tile (32 b128/wave, +8 vs r5), pre-barrier lgkmcnt(8)
// throttle on the 12-read phases, plain s_barrier + compiler counted
// lgkmcnt (r5-verified). Staging: P1 -> {B0-3,a1,a3}(t+1) into NXT;
// P3 -> {a0,a2}(t+2) into CUR. Single VMW(2) at P4 retires exactly
// tile-(t+1)'s 8 loads, 3-phase latency cover. Race-free by barriers:
// B-NXT last read at t-1's P4 (1 barrier before P1 stage); a0a2-CUR
// last read at P1 (2 barriers before P3 stage); a1a3-NXT last read at
// t-1's P3. XOR-swizzled LDS (conflict-free, verified rounds 2-5).

#define VMW(N) asm volatile("s_waitcnt vmcnt(" #N ")" ::: "memory")
#define LGKM8 asm volatile("s_waitcnt lgkmcnt(8)" ::: "memory")
#define BAR __builtin_amdgcn_s_barrier()

// read A fragments for m-half MH (8 x ds_read_b128): af[0..3][kk]
#define RDA4(BUFO, MH) \
  _Pragma("unroll") for (int mi = 0; mi < 4; ++mi) \
  _Pragma("unroll") for (int kk = 0; kk < 2; ++kk) \
    af[mi][kk] = *(const short8*)(lds + (BUFO) + \
        (wm * 128 + ((MH) * 4 + mi) * 16 + r16) * 128 + (acol0 ^ (kk << 6)));

// read B fragments for n-half NH (4 x ds_read_b128): bf[0..1][kk]
#define RDB2(BUFO, NH) \
  _Pragma("unroll") for (int ni = 0; ni < 2; ++ni) \
  _Pragma("unroll") for (int kk = 0; kk < 2; ++kk) \
    bf[ni][kk] = *(const short8*)(lds + (BUFO) + 32768 + \
        (wn * 64 + ((NH) * 2 + ni) * 16 + r16) * 128 + (acol0 ^ (kk << 6)));

// 16 MFMA for quadrant (MH, NH), setprio bracket (T5)
#define FMQ2(MH, NH) do { \
  __builtin_amdgcn_s_setprio(1); \
  _Pragma("unroll") for (int kk = 0; kk < 2; ++kk) \
  _Pragma("unroll") for (int mi = 0; mi < 4; ++mi) \
  _Pragma("unroll") for (int ni = 0; ni < 2; ++ni) \
    acc[(MH) * 4 + mi][(NH) * 2 + ni] = __builtin_amdgcn_mfma_f32_16x16x32_bf16( \
        af[mi][kk], bf[ni][kk], acc[(MH) * 4 + mi][(NH) * 2 + ni], 0, 0, 0); \
  __builtin_amdgcn_s_setprio(0); \
} while (0)

// One K-tile (4 quadrant phases).
#define ITER(CUR, NXT, T) do { \
  /* P1: quadrant (m0,n0); stage t+1's B0-3 + a1,a3 into NXT */ \
  RDA4(CUR, 0); RDB2(CUR, 0); \
  stB(NXT, 0, (T) + 1); stB(NXT, 1, (T) + 1); \
  stB(NXT, 2, (T) + 1); stB(NXT, 3, (T) + 1); \
  stA(NXT, 1, (T) + 1); stA(NXT, 3, (T) + 1); \
  LGKM8; BAR; FMQ2(0, 0); BAR; \
  /* P2: quadrant (m0,n1) */ \
  RDB2(CUR, 1); \
  BAR; FMQ2(0, 1); BAR; \
  /* P3: quadrant (m1,n0), B-h0 re-read; stage t+2's a0,a2 into CUR */ \
  RDA4(CUR, 1); RDB2(CUR, 0); \
  stA(CUR, 0, (T) + 2); stA(CUR, 2, (T) + 2); \
  LGKM8; BAR; FMQ2(1, 0); BAR; \
  /* P4: quadrant (m1,n1), B-h1 re-read; single counted vmcnt */ \
  RDB2(CUR, 1); \
  VMW(2); BAR; FMQ2(1, 1); BAR; \
} while (0)

__global__ __launch_bounds__(512, 2)
void gemm_bt(const unsigned short* __restrict__ A,
             const unsigned short* __restrict__ B,
             const float* __restrict__ bias,
             float* __restrict__ C) {
  __shared__ char lds[131072];  // 2 bufs x (A 32K | B 32K)
  const int tid = threadIdx.x;
  const int lane = tid & 63;
  const int w = tid >> 6;       // 0..7
  const int wm = w >> 2;        // 0..1  (wave row: 128 rows)
  const int wn = w & 3;         // 0..3  (wave col: 64 cols)
  const int r16 = lane & 15;
  const int g = lane >> 4;
  const int acol0 = (g << 4) ^ ((r16 & 7) << 4);

  // XCD-bijective block swizzle (512 % 8 == 0), bn-major chunks for B-panel L2 reuse
  const int s = (int)blockIdx.x;
  const int wg = (s & 7) * 64 + (s >> 3);
  const int bm = wg & 31;
  const int bn = wg >> 5;

  const char* Abase = (const char*)A + (size_t)bm * 256 * K2;
  const char* Bbase = (const char*)B + (size_t)bn * 256 * K2;

  // staging: chunk = 64 rows x 128 B = 8 KiB; one gld16 per thread per chunk.
  // Inverse-swizzled global source, linear LDS dest (rule #21).
  const int strow = tid >> 3;
  const int scol = ((tid & 7) * 16) ^ ((strow & 7) << 4);
  const int sdst = w * 1024;

  auto stA = [&](int bo, int c, int kt) {
    gld16(Abase + (size_t)(c * 64 + strow) * K2 + kt * 128 + scol,
          lds + bo + c * 8192 + sdst);
  };
  auto stB = [&](int bo, int c, int kt) {
    gld16(Bbase + (size_t)(c * 64 + strow) * K2 + kt * 128 + scol,
          lds + bo + 32768 + c * 8192 + sdst);
  };

  f32x4 acc[8][4] = {};
  short8 af[4][2];
  short8 bf[2][2];

  // prologue: tile0 full (8 chunks) + tile1's a0,a2 (the P3-role loads);
  // VMW(2) retires tile0's 8, leaves tile1-a0a2 in flight (steady invariant).
  stB(0, 0, 0); stB(0, 1, 0); stB(0, 2, 0); stB(0, 3, 0);
  stA(0, 0, 0); stA(0, 1, 0); stA(0, 2, 0); stA(0, 3, 0);
  stA(65536, 0, 1); stA(65536, 2, 1);
  VMW(2); BAR;

  // tiles 0..61 as 31 even/odd pairs
  for (int tp = 0; tp < 31; ++tp) {
    ITER(0, 65536, 2 * tp);
    ITER(65536, 0, 2 * tp + 1);
  }
  // tile 62 (CUR=0): P1 stages t63's B,a1,a3; P3 stage skipped; P4 VMW(0)
  RDA4(0, 0); RDB2(0, 0);
  stB(65536, 0, 63); stB(65536, 1, 63);
  stB(65536, 2, 63); stB(65536, 3, 63);
  stA(65536, 1, 63); stA(65536, 3, 63);
  LGKM8; BAR; FMQ2(0, 0); BAR;
  RDB2(0, 1);
  BAR; FMQ2(0, 1); BAR;
  RDA4(0, 1); RDB2(0, 0);
  LGKM8; BAR; FMQ2(1, 0); BAR;
  RDB2(0, 1);
  VMW(0); BAR; FMQ2(1, 1); BAR;
  // tile 63 (buf 1): pure reads, all data resident, no barriers needed
  RDA4(65536, 0); RDB2(65536, 0);
  FMQ2(0, 0);
  RDB2(65536, 1);
  FMQ2(0, 1);
  RDA4(65536, 1); RDB2(65536, 0);
  FMQ2(1, 0);
  RDB2(65536, 1);
  FMQ2(1, 1);

  // epilogue: C/D layout col = lane&15, row = (lane>>4)*4 + j  [m89-verified]
  const int cb0 = bn * 256 + wn * 64 + r16;
  float bv[4];
#pragma unroll
  for (int n = 0; n < 4; ++n) bv[n] = bias[cb0 + n * 16];
#pragma unroll
  for (int m = 0; m < 8; ++m) {
#pragma unroll
    for (int j = 0; j < 4; ++j) {
      int row = bm * 256 + wm * 128 + m * 16 + g * 4 + j;
      float* Crow = C + (size_t)row * N_DIM + cb0;
#pragma unroll
      for (int n = 0; n < 4; ++n) Crow[n * 16] = acc[m][n][j] + bv[n];
    }
  }
}

extern "C" void kernel_launch(void* const* d_in, const int* in_sizes, int n_in,
                              void* d_out, int out_size, void* d_ws, size_t ws_size,
                              hipStream_t stream) {
  const float* x     = (const float*)d_in[0];
  const float* cb    = (const float*)d_in[1];
  const int*   idx   = (const int*)d_in[2];
  const int*   base  = (const int*)d_in[3];
  const float* scale = (const float*)d_in[4];
  const float* zero  = (const float*)d_in[5];
  const float* bias  = (const float*)d_in[6];
  float* out = (float*)d_out;

  // workspace: Wq bf16 [N,K] (32 MiB) | x bf16 [M,K] (64 MiB)
  unsigned short* Wq = (unsigned short*)d_ws;
  unsigned short* Xb = (unsigned short*)((char*)d_ws + (size_t)N_DIM * K_DIM * 2);

  const int prep_blocks = L_BLK / 256 + (M_DIM * K_DIM / 8) / 256;
  prep_kernel<<<prep_blocks, 256, 0, stream>>>(cb, idx, base, scale, zero, x, Wq, Xb);
  gemm_bt<<<(M_DIM / 256) * (N_DIM / 256), 512, 0, stream>>>(Xb, Wq, bias, out);
}